// Round 3
// baseline (1249.364 us; speedup 1.0000x reference)
//
#include <hip/hip_runtime.h>

// ---- problem constants ----
#define T_LEN   240
#define B_SZ    8
#define NFILT   2560
#define KD      9216          // 96*96
#define M_DIM   1920          // B*T
#define N_DIM   5120          // 2*NF (sin | cos)
#define PAD_L   8
#define KSPLIT  2
#define KHALF   4608

typedef unsigned short u16;
typedef __attribute__((ext_vector_type(8)))  __bf16 bf16x8;
typedef __attribute__((ext_vector_type(16))) float  f32x16;

// ---------- fp32 -> (hi,lo) bf16 split, RNE both halves ----------
__device__ __forceinline__ u16 f2bf_rne(float f) {
    unsigned u = __float_as_uint(f);
    u += 0x7FFFu + ((u >> 16) & 1u);
    return (u16)(u >> 16);
}

__device__ __forceinline__ void split4(const float* __restrict__ src,
                                       u16* __restrict__ hi, u16* __restrict__ lo, int i) {
    const float4 v = ((const float4*)src)[i];
    float vv[4] = {v.x, v.y, v.z, v.w};
    u16 hh[4], ll[4];
#pragma unroll
    for (int j = 0; j < 4; ++j) {
        unsigned u = __float_as_uint(vv[j]);
        unsigned r = u + 0x7FFFu + ((u >> 16) & 1u);
        u16 hb = (u16)(r >> 16);
        float hf = __uint_as_float((unsigned)hb << 16);
        hh[j] = hb;
        ll[j] = f2bf_rne(vv[j] - hf);   // residual exact in fp32, then RNE
    }
    ushort4 h, l;
    h.x = hh[0]; h.y = hh[1]; h.z = hh[2]; h.w = hh[3];
    l.x = ll[0]; l.y = ll[1]; l.z = ll[2]; l.w = ll[3];
    ((ushort4*)hi)[i] = h;
    ((ushort4*)lo)[i] = l;
}

// one fused launch: x | w_sin | w_cos regions
#define NX4  (17694720 / 4)
#define NW4  (23592960 / 4)
__global__ void split_all_kernel(const float* __restrict__ x,
                                 const float* __restrict__ wss,
                                 const float* __restrict__ wsc,
                                 u16* __restrict__ xh, u16* __restrict__ xl,
                                 u16* __restrict__ wh, u16* __restrict__ wl) {
    int i = blockIdx.x * 256 + threadIdx.x;
    if (i < NX4) {
        split4(x, xh, xl, i);
    } else if (i < NX4 + NW4) {
        split4(wss, wh, wl, i - NX4);
    } else if (i < NX4 + 2 * NW4) {
        int j = i - NX4 - NW4;
        split4(wsc, wh + (size_t)NFILT * KD, wl + (size_t)NFILT * KD, j);
    }
}

// ---------- async global->LDS, 16B per lane ----------
__device__ __forceinline__ void glds16(const u16* gp, __bf16* lp) {
    __builtin_amdgcn_global_load_lds(
        (const __attribute__((address_space(1))) void*)gp,
        (__attribute__((address_space(3))) void*)lp, 16, 0, 0);
}

// ---------- bf16x3 split GEMM: C = Ah*Bh + Ah*Bl + Al*Bh  (32x32x16 MFMA, split-K=2) ----------
// XOR-swizzled LDS: chunk c (16B) holds row=c>>2, kgroup=(c&3)^((c>>2)&3).
// Staging picks the swizzled global k-chunk per lane; compute reads at
// offset ((fo>>3)^(row&3))*8 -> bank classes perfectly even (conflict-free).
__global__ __launch_bounds__(256, 4) void gemm_split_kernel(
    const u16* __restrict__ xh, const u16* __restrict__ xl,
    const u16* __restrict__ wh, const u16* __restrict__ wl,
    float* __restrict__ g) {

    __shared__ __align__(16) __bf16 sAh[128 * 32];
    __shared__ __align__(16) __bf16 sAl[128 * 32];
    __shared__ __align__(16) __bf16 sBh[128 * 32];
    __shared__ __align__(16) __bf16 sBl[128 * 32];

    const int tid = threadIdx.x;
    const int l   = tid & 63;
    const int w   = tid >> 6;
    const int tb  = blockIdx.x % 600;
    const int kbase = (blockIdx.x / 600) * KHALF;   // split-K slice
    const int m0  = (tb / 40) * 128;                // 15 m-tiles
    const int n0  = (tb % 40) * 128;                // 40 n-tiles

    // staging: lane l writes LDS chunk (w*64 + l); global k-chunk is XOR-swizzled
    const int srow = w * 16 + (l >> 2);
    const int skc  = (((l & 3) ^ ((l >> 2) & 3)) * 8);   // swizzled k-element offset
    const size_t aOff0 = (size_t)(m0 + srow) * KD + skc + kbase;
    const size_t aOff1 = aOff0 + (size_t)64 * KD;
    const size_t bOff0 = (size_t)(n0 + srow) * KD + skc + kbase;
    const size_t bOff1 = bOff0 + (size_t)64 * KD;
    const int ldsOff0 = w * 512 + l * 8;          // == hw layout: base + lane*16B
    const int ldsOff1 = ldsOff0 + 64 * 32;

    // compute mapping: wave (wr,wc) owns 64x64 = 2x2 tiles of 32x32x16
    const int wr = (w >> 1) * 64;
    const int wc = (w & 1) * 64;
    const int rowin = l & 31;          // A/B fragment: m(or n) = lane&31
    const int rsw   = l & 3;           // row&3 for swizzle
    const int kq    = l >> 5;          // 0/1: k-chunk within 16-wide substep

    f32x16 acc[2][2];
#pragma unroll
    for (int i = 0; i < 2; ++i)
#pragma unroll
        for (int j = 0; j < 2; ++j)
#pragma unroll
            for (int r = 0; r < 16; ++r)
                acc[i][j][r] = 0.f;

    for (int kt = 0; kt < KHALF; kt += 32) {
        glds16(xh + aOff0 + kt, &sAh[ldsOff0]);
        glds16(xh + aOff1 + kt, &sAh[ldsOff1]);
        glds16(xl + aOff0 + kt, &sAl[ldsOff0]);
        glds16(xl + aOff1 + kt, &sAl[ldsOff1]);
        glds16(wh + bOff0 + kt, &sBh[ldsOff0]);
        glds16(wh + bOff1 + kt, &sBh[ldsOff1]);
        glds16(wl + bOff0 + kt, &sBl[ldsOff0]);
        glds16(wl + bOff1 + kt, &sBl[ldsOff1]);
        __syncthreads();

#pragma unroll
        for (int ks = 0; ks < 2; ++ks) {           // two 16-wide k substeps
            const int kg = ks * 2 + kq;            // logical k-chunk 0..3
            const int ko = ((kg ^ rsw) * 8);       // swizzled element offset
            bf16x8 ah[2], al[2], bh[2], bl[2];
#pragma unroll
            for (int t = 0; t < 2; ++t) {
                const int ra = (wr + t * 32 + rowin) * 32 + ko;
                const int rb = (wc + t * 32 + rowin) * 32 + ko;
                ah[t] = *(const bf16x8*)&sAh[ra];
                al[t] = *(const bf16x8*)&sAl[ra];
                bh[t] = *(const bf16x8*)&sBh[rb];
                bl[t] = *(const bf16x8*)&sBl[rb];
            }
#pragma unroll
            for (int tr = 0; tr < 2; ++tr)
#pragma unroll
                for (int tc = 0; tc < 2; ++tc) {
                    acc[tr][tc] = __builtin_amdgcn_mfma_f32_32x32x16_bf16(ah[tr], bh[tc], acc[tr][tc], 0, 0, 0);
                    acc[tr][tc] = __builtin_amdgcn_mfma_f32_32x32x16_bf16(ah[tr], bl[tc], acc[tr][tc], 0, 0, 0);
                    acc[tr][tc] = __builtin_amdgcn_mfma_f32_32x32x16_bf16(al[tr], bh[tc], acc[tr][tc], 0, 0, 0);
                }
        }
        __syncthreads();
    }

    // epilogue: 32x32 C/D layout col = l&31, row = (r&3) + 8*(r>>2) + 4*(l>>5)  (m74/m101)
    const int cbase = (l >> 5) * 4;
    const int ccol  = l & 31;
#pragma unroll
    for (int tr = 0; tr < 2; ++tr)
#pragma unroll
        for (int tc = 0; tc < 2; ++tc) {
            const int col = n0 + wc + tc * 32 + ccol;
#pragma unroll
            for (int r = 0; r < 16; ++r) {
                const int row = m0 + wr + tr * 32 + (r & 3) + 8 * (r >> 2) + cbase;
                atomicAdd(g + (size_t)row * N_DIM + col, acc[tr][tc][r]);
            }
        }
}

// ---------- depthwise temporal conv (cross-corr, pad 8/7) + energy, float4 ----------
__global__ void conv_energy_kernel(const float* __restrict__ g,
                                   const float* __restrict__ wts,
                                   const float* __restrict__ wtc,
                                   float* __restrict__ out) {
    const int idx4 = blockIdx.x * 256 + threadIdx.x;     // one thread = 4 filters
    const int nf4  = NFILT / 4;
    const int f4   = idx4 % nf4;
    const int bt   = idx4 / nf4;
    const int t    = bt % T_LEN;
    const int b    = bt / T_LEN;
    const int f    = f4 * 4;
    const float* grow = g + (size_t)b * T_LEN * N_DIM + f;
    float s[4] = {0.f, 0.f, 0.f, 0.f}, c[4] = {0.f, 0.f, 0.f, 0.f};
#pragma unroll
    for (int j = 0; j < 16; ++j) {
        const int tt = t + j - PAD_L;
        if (tt >= 0 && tt < T_LEN) {   // uniform across the block
            const float4 gs = *(const float4*)(grow + (size_t)tt * N_DIM);
            const float4 gc = *(const float4*)(grow + (size_t)tt * N_DIM + NFILT);
            const float gsv[4] = {gs.x, gs.y, gs.z, gs.w};
            const float gcv[4] = {gc.x, gc.y, gc.z, gc.w};
#pragma unroll
            for (int q = 0; q < 4; ++q) {
                const float a  = wtc[(f + q) * 16 + j];
                const float bb = wts[(f + q) * 16 + j];
                s[q] += gsv[q] * a + gcv[q] * bb;
                c[q] += gcv[q] * a - gsv[q] * bb;
            }
        }
    }
    float4 o;
    float ov[4];
#pragma unroll
    for (int q = 0; q < 4; ++q) {
        const float r = sqrtf(s[q] * s[q] + c[q] * c[q]);
        ov[q] = logf(r + 1e-5f);
    }
    o.x = ov[0]; o.y = ov[1]; o.z = ov[2]; o.w = ov[3];
    *(float4*)(out + (size_t)idx4 * 4) = o;
}

extern "C" void kernel_launch(void* const* d_in, const int* in_sizes, int n_in,
                              void* d_out, int out_size, void* d_ws, size_t ws_size,
                              hipStream_t stream) {
    const float* x   = (const float*)d_in[0];  // (8,240,96,96)
    const float* wss = (const float*)d_in[1];  // (2560,96,96)
    const float* wsc = (const float*)d_in[2];  // (2560,96,96)
    const float* wts = (const float*)d_in[3];  // (2560,16)
    const float* wtc = (const float*)d_in[4];  // (2560,16)
    float* out = (float*)d_out;

    // workspace layout (bytes):
    //   xh: 35,389,440 | xl: 35,389,440 | wh: 94,371,840 | wl: 94,371,840 | g: 39,321,600
    char* ws = (char*)d_ws;
    u16*   xh  = (u16*)(ws);
    u16*   xl  = (u16*)(ws + 35389440);
    u16*   whi = (u16*)(ws + 70778880);
    u16*   wlo = (u16*)(ws + 165150720);
    float* g   = (float*)(ws + 259522560);

    hipMemsetAsync(g, 0, (size_t)M_DIM * N_DIM * 4, stream);

    const int ntot4 = NX4 + 2 * NW4;
    split_all_kernel<<<(ntot4 + 255) / 256, 256, 0, stream>>>(x, wss, wsc, xh, xl, whi, wlo);

    gemm_split_kernel<<<600 * KSPLIT, 256, 0, stream>>>(xh, xl, whi, wlo, g);

    conv_energy_kernel<<<(B_SZ * T_LEN * NFILT / 4) / 256, 256, 0, stream>>>(g, wts, wtc, out);
}

// Round 4
// 1017.658 us; speedup vs baseline: 1.2277x; 1.2277x over previous
//
#include <hip/hip_runtime.h>

// ---- problem constants ----
#define T_LEN   240
#define B_SZ    8
#define NFILT   2560
#define KD      9216          // 96*96
#define M_DIM   1920          // B*T
#define N_DIM   5120          // 2*NF (sin | cos)
#define PAD_L   8

typedef unsigned short u16;
typedef __attribute__((ext_vector_type(8)))  __bf16 bf16x8;
typedef __attribute__((ext_vector_type(16))) float  f32x16;

// ---------- fp32 -> (hi,lo) bf16 split, RNE both halves ----------
__device__ __forceinline__ u16 f2bf_rne(float f) {
    unsigned u = __float_as_uint(f);
    u += 0x7FFFu + ((u >> 16) & 1u);
    return (u16)(u >> 16);
}

__device__ __forceinline__ void split4(const float* __restrict__ src,
                                       u16* __restrict__ hi, u16* __restrict__ lo, int i) {
    const float4 v = ((const float4*)src)[i];
    float vv[4] = {v.x, v.y, v.z, v.w};
    u16 hh[4], ll[4];
#pragma unroll
    for (int j = 0; j < 4; ++j) {
        unsigned u = __float_as_uint(vv[j]);
        unsigned r = u + 0x7FFFu + ((u >> 16) & 1u);
        u16 hb = (u16)(r >> 16);
        float hf = __uint_as_float((unsigned)hb << 16);
        hh[j] = hb;
        ll[j] = f2bf_rne(vv[j] - hf);   // residual exact in fp32, then RNE
    }
    ushort4 h, l;
    h.x = hh[0]; h.y = hh[1]; h.z = hh[2]; h.w = hh[3];
    l.x = ll[0]; l.y = ll[1]; l.z = ll[2]; l.w = ll[3];
    ((ushort4*)hi)[i] = h;
    ((ushort4*)lo)[i] = l;
}

// one fused launch: x | w_sin | w_cos regions
#define NX4  (17694720 / 4)
#define NW4  (23592960 / 4)
__global__ void split_all_kernel(const float* __restrict__ x,
                                 const float* __restrict__ wss,
                                 const float* __restrict__ wsc,
                                 u16* __restrict__ xh, u16* __restrict__ xl,
                                 u16* __restrict__ wh, u16* __restrict__ wl) {
    int i = blockIdx.x * 256 + threadIdx.x;
    if (i < NX4) {
        split4(x, xh, xl, i);
    } else if (i < NX4 + NW4) {
        split4(wss, wh, wl, i - NX4);
    } else if (i < NX4 + 2 * NW4) {
        int j = i - NX4 - NW4;
        split4(wsc, wh + (size_t)NFILT * KD, wl + (size_t)NFILT * KD, j);
    }
}

// ---------- async global->LDS, 16B per lane ----------
__device__ __forceinline__ void glds16(const u16* gp, __bf16* lp) {
    __builtin_amdgcn_global_load_lds(
        (const __attribute__((address_space(1))) void*)gp,
        (__attribute__((address_space(3))) void*)lp, 16, 0, 0);
}

// ---------- bf16x3 split GEMM: C = Ah*Bh + Ah*Bl + Al*Bh  (32x32x16 MFMA) ----------
// XOR-swizzled LDS staging (kept from R3; neutral but harmless).
__global__ __launch_bounds__(256, 4) void gemm_split_kernel(
    const u16* __restrict__ xh, const u16* __restrict__ xl,
    const u16* __restrict__ wh, const u16* __restrict__ wl,
    float* __restrict__ g) {

    __shared__ __align__(16) __bf16 sAh[128 * 32];
    __shared__ __align__(16) __bf16 sAl[128 * 32];
    __shared__ __align__(16) __bf16 sBh[128 * 32];
    __shared__ __align__(16) __bf16 sBl[128 * 32];

    const int tid = threadIdx.x;
    const int l   = tid & 63;
    const int w   = tid >> 6;
    const int m0  = (blockIdx.x / 40) * 128;        // 15 m-tiles
    const int n0  = (blockIdx.x % 40) * 128;        // 40 n-tiles

    // staging: lane l fills LDS chunk (w*64 + l); global k-chunk XOR-swizzled
    const int srow = w * 16 + (l >> 2);
    const int skc  = (((l & 3) ^ ((l >> 2) & 3)) * 8);
    const size_t aOff0 = (size_t)(m0 + srow) * KD + skc;
    const size_t aOff1 = aOff0 + (size_t)64 * KD;
    const size_t bOff0 = (size_t)(n0 + srow) * KD + skc;
    const size_t bOff1 = bOff0 + (size_t)64 * KD;
    const int ldsOff0 = w * 512 + l * 8;
    const int ldsOff1 = ldsOff0 + 64 * 32;

    // compute mapping: wave (wr,wc) owns 64x64 = 2x2 tiles of 32x32x16
    const int wr = (w >> 1) * 64;
    const int wc = (w & 1) * 64;
    const int rowin = l & 31;
    const int rsw   = l & 3;
    const int kq    = l >> 5;

    f32x16 acc[2][2];
#pragma unroll
    for (int i = 0; i < 2; ++i)
#pragma unroll
        for (int j = 0; j < 2; ++j)
#pragma unroll
            for (int r = 0; r < 16; ++r)
                acc[i][j][r] = 0.f;

    for (int kt = 0; kt < KD; kt += 32) {
        glds16(xh + aOff0 + kt, &sAh[ldsOff0]);
        glds16(xh + aOff1 + kt, &sAh[ldsOff1]);
        glds16(xl + aOff0 + kt, &sAl[ldsOff0]);
        glds16(xl + aOff1 + kt, &sAl[ldsOff1]);
        glds16(wh + bOff0 + kt, &sBh[ldsOff0]);
        glds16(wh + bOff1 + kt, &sBh[ldsOff1]);
        glds16(wl + bOff0 + kt, &sBl[ldsOff0]);
        glds16(wl + bOff1 + kt, &sBl[ldsOff1]);
        __syncthreads();

#pragma unroll
        for (int ks = 0; ks < 2; ++ks) {           // two 16-wide k substeps
            const int kg = ks * 2 + kq;            // logical k-chunk 0..3
            const int ko = ((kg ^ rsw) * 8);       // swizzled element offset
            bf16x8 ah[2], al[2], bh[2], bl[2];
#pragma unroll
            for (int t = 0; t < 2; ++t) {
                const int ra = (wr + t * 32 + rowin) * 32 + ko;
                const int rb = (wc + t * 32 + rowin) * 32 + ko;
                ah[t] = *(const bf16x8*)&sAh[ra];
                al[t] = *(const bf16x8*)&sAl[ra];
                bh[t] = *(const bf16x8*)&sBh[rb];
                bl[t] = *(const bf16x8*)&sBl[rb];
            }
#pragma unroll
            for (int tr = 0; tr < 2; ++tr)
#pragma unroll
                for (int tc = 0; tc < 2; ++tc) {
                    acc[tr][tc] = __builtin_amdgcn_mfma_f32_32x32x16_bf16(ah[tr], bh[tc], acc[tr][tc], 0, 0, 0);
                    acc[tr][tc] = __builtin_amdgcn_mfma_f32_32x32x16_bf16(ah[tr], bl[tc], acc[tr][tc], 0, 0, 0);
                    acc[tr][tc] = __builtin_amdgcn_mfma_f32_32x32x16_bf16(al[tr], bh[tc], acc[tr][tc], 0, 0, 0);
                }
        }
        __syncthreads();
    }

    // epilogue: 32x32 C/D layout col = l&31, row = (r&3) + 8*(r>>2) + 4*(l>>5)
    const int cbase = (l >> 5) * 4;
    const int ccol  = l & 31;
#pragma unroll
    for (int tr = 0; tr < 2; ++tr)
#pragma unroll
        for (int tc = 0; tc < 2; ++tc) {
            const int col = n0 + wc + tc * 32 + ccol;
#pragma unroll
            for (int r = 0; r < 16; ++r) {
                const int row = m0 + wr + tr * 32 + (r & 3) + 8 * (r >> 2) + cbase;
                g[(size_t)row * N_DIM + col] = acc[tr][tc][r];
            }
        }
}

// ---------- depthwise temporal conv + energy, LDS-staged weights ----------
// block = one (b, t, 256-filter chunk); thread = one filter.
// weights staged transposed in LDS: wl[tap][filter] -> conflict-free reads.
__global__ __launch_bounds__(256) void conv_energy_kernel(
    const float* __restrict__ g,
    const float* __restrict__ wts,
    const float* __restrict__ wtc,
    float* __restrict__ out) {

    __shared__ float wl_c[16][256];
    __shared__ float wl_s[16][256];

    const int tid = threadIdx.x;
    const int bid = blockIdx.x;          // 19200 = 8 * 240 * 10
    const int fc  = bid % 10;
    const int t   = (bid / 10) % T_LEN;
    const int b   = bid / (10 * T_LEN);
    const int f0  = fc * 256;

    // cooperative weight load: thread tid owns filter f0+tid's 16 taps (4 float4 each)
    {
        const float4* wrc = (const float4*)(wtc + (size_t)(f0 + tid) * 16);
        const float4* wrs = (const float4*)(wts + (size_t)(f0 + tid) * 16);
#pragma unroll
        for (int k4 = 0; k4 < 4; ++k4) {
            const float4 vc = wrc[k4];
            const float4 vs = wrs[k4];
            wl_c[k4 * 4 + 0][tid] = vc.x; wl_c[k4 * 4 + 1][tid] = vc.y;
            wl_c[k4 * 4 + 2][tid] = vc.z; wl_c[k4 * 4 + 3][tid] = vc.w;
            wl_s[k4 * 4 + 0][tid] = vs.x; wl_s[k4 * 4 + 1][tid] = vs.y;
            wl_s[k4 * 4 + 2][tid] = vs.z; wl_s[k4 * 4 + 3][tid] = vs.w;
        }
    }
    __syncthreads();

    const float* grow = g + (size_t)b * T_LEN * N_DIM + f0 + tid;
    float s = 0.f, c = 0.f;
#pragma unroll
    for (int j = 0; j < 16; ++j) {
        const int tt = t + j - PAD_L;
        if (tt >= 0 && tt < T_LEN) {     // block-uniform branch (t fixed per block)
            const float gs = grow[(size_t)tt * N_DIM];
            const float gc = grow[(size_t)tt * N_DIM + NFILT];
            const float a  = wl_c[j][tid];
            const float bb = wl_s[j][tid];
            s += gs * a + gc * bb;
            c += gc * a - gs * bb;
        }
    }
    const float r = sqrtf(s * s + c * c);
    out[(size_t)((b * T_LEN + t) * NFILT) + f0 + tid] = logf(r + 1e-5f);
}

extern "C" void kernel_launch(void* const* d_in, const int* in_sizes, int n_in,
                              void* d_out, int out_size, void* d_ws, size_t ws_size,
                              hipStream_t stream) {
    const float* x   = (const float*)d_in[0];  // (8,240,96,96)
    const float* wss = (const float*)d_in[1];  // (2560,96,96)
    const float* wsc = (const float*)d_in[2];  // (2560,96,96)
    const float* wts = (const float*)d_in[3];  // (2560,16)
    const float* wtc = (const float*)d_in[4];  // (2560,16)
    float* out = (float*)d_out;

    // workspace layout (bytes):
    //   xh: 35,389,440 | xl: 35,389,440 | wh: 94,371,840 | wl: 94,371,840 | g: 39,321,600
    char* ws = (char*)d_ws;
    u16*   xh  = (u16*)(ws);
    u16*   xl  = (u16*)(ws + 35389440);
    u16*   whi = (u16*)(ws + 70778880);
    u16*   wlo = (u16*)(ws + 165150720);
    float* g   = (float*)(ws + 259522560);

    const int ntot4 = NX4 + 2 * NW4;
    split_all_kernel<<<(ntot4 + 255) / 256, 256, 0, stream>>>(x, wss, wsc, xh, xl, whi, wlo);

    gemm_split_kernel<<<600, 256, 0, stream>>>(xh, xl, whi, wlo, g);

    conv_energy_kernel<<<B_SZ * T_LEN * 10, 256, 0, stream>>>(g, wts, wtc, out);
}

// Round 5
// 1007.983 us; speedup vs baseline: 1.2395x; 1.0096x over previous
//
#include <hip/hip_runtime.h>

// ---- problem constants ----
#define T_LEN   240
#define B_SZ    8
#define NFILT   2560
#define KD      9216          // 96*96
#define M_DIM   1920          // B*T
#define N_DIM   5120          // 2*NF (sin | cos)
#define PAD_L   8
#define KSPLIT  3
#define KSLICE  3072          // KD / KSPLIT

typedef unsigned short u16;
typedef __attribute__((ext_vector_type(8)))  __bf16 bf16x8;
typedef __attribute__((ext_vector_type(16))) float  f32x16;

// ---------- fp32 -> (hi,lo) bf16 split, RNE both halves ----------
__device__ __forceinline__ u16 f2bf_rne(float f) {
    unsigned u = __float_as_uint(f);
    u += 0x7FFFu + ((u >> 16) & 1u);
    return (u16)(u >> 16);
}

__device__ __forceinline__ void split4(const float* __restrict__ src,
                                       u16* __restrict__ hi, u16* __restrict__ lo, int i) {
    const float4 v = ((const float4*)src)[i];
    float vv[4] = {v.x, v.y, v.z, v.w};
    u16 hh[4], ll[4];
#pragma unroll
    for (int j = 0; j < 4; ++j) {
        unsigned u = __float_as_uint(vv[j]);
        unsigned r = u + 0x7FFFu + ((u >> 16) & 1u);
        u16 hb = (u16)(r >> 16);
        float hf = __uint_as_float((unsigned)hb << 16);
        hh[j] = hb;
        ll[j] = f2bf_rne(vv[j] - hf);   // residual exact in fp32, then RNE
    }
    ushort4 h, l;
    h.x = hh[0]; h.y = hh[1]; h.z = hh[2]; h.w = hh[3];
    l.x = ll[0]; l.y = ll[1]; l.z = ll[2]; l.w = ll[3];
    ((ushort4*)hi)[i] = h;
    ((ushort4*)lo)[i] = l;
}

// one fused launch: x | w_sin | w_cos regions
#define NX4  (17694720 / 4)
#define NW4  (23592960 / 4)
__global__ void split_all_kernel(const float* __restrict__ x,
                                 const float* __restrict__ wss,
                                 const float* __restrict__ wsc,
                                 u16* __restrict__ xh, u16* __restrict__ xl,
                                 u16* __restrict__ wh, u16* __restrict__ wl) {
    int i = blockIdx.x * 256 + threadIdx.x;
    if (i < NX4) {
        split4(x, xh, xl, i);
    } else if (i < NX4 + NW4) {
        split4(wss, wh, wl, i - NX4);
    } else if (i < NX4 + 2 * NW4) {
        int j = i - NX4 - NW4;
        split4(wsc, wh + (size_t)NFILT * KD, wl + (size_t)NFILT * KD, j);
    }
}

// ---------- async global->LDS, 16B per lane ----------
__device__ __forceinline__ void glds16(const u16* gp, __bf16* lp) {
    __builtin_amdgcn_global_load_lds(
        (const __attribute__((address_space(1))) void*)gp,
        (__attribute__((address_space(3))) void*)lp, 16, 0, 0);
}

// ---------- bf16x3 split GEMM: C = Ah*Bh + Ah*Bl + Al*Bh  (32x32x16 MFMA, split-K=3) ----------
__global__ __launch_bounds__(256, 4) void gemm_split_kernel(
    const u16* __restrict__ xh, const u16* __restrict__ xl,
    const u16* __restrict__ wh, const u16* __restrict__ wl,
    float* __restrict__ g) {

    __shared__ __align__(16) __bf16 sAh[128 * 32];
    __shared__ __align__(16) __bf16 sAl[128 * 32];
    __shared__ __align__(16) __bf16 sBh[128 * 32];
    __shared__ __align__(16) __bf16 sBl[128 * 32];

    const int tid = threadIdx.x;
    const int l   = tid & 63;
    const int w   = tid >> 6;
    const int tb  = blockIdx.x % 600;
    const int kbase = (blockIdx.x / 600) * KSLICE;  // split-K slice
    const int m0  = (tb / 40) * 128;                // 15 m-tiles
    const int n0  = (tb % 40) * 128;                // 40 n-tiles

    // staging: tile[128][32] bf16 row-major; lane l writes LDS base + l*16B
    const int srow = w * 16 + (l >> 2);
    const int skc  = (l & 3) * 8;
    const size_t aOff0 = (size_t)(m0 + srow) * KD + skc + kbase;
    const size_t aOff1 = aOff0 + (size_t)64 * KD;
    const size_t bOff0 = (size_t)(n0 + srow) * KD + skc + kbase;
    const size_t bOff1 = bOff0 + (size_t)64 * KD;
    const int ldsOff0 = srow * 32 + skc;
    const int ldsOff1 = ldsOff0 + 64 * 32;

    // compute mapping: wave (wr,wc) owns 64x64 = 2x2 tiles of 32x32x16
    const int wr = (w >> 1) * 64;
    const int wc = (w & 1) * 64;
    const int rowin = l & 31;          // A/B fragment: m(or n) = lane&31
    const int kq    = (l >> 5) * 8;    // k base within 16-wide substep

    f32x16 acc[2][2];
#pragma unroll
    for (int i = 0; i < 2; ++i)
#pragma unroll
        for (int j = 0; j < 2; ++j)
#pragma unroll
            for (int r = 0; r < 16; ++r)
                acc[i][j][r] = 0.f;

    for (int kt = 0; kt < KSLICE; kt += 32) {
        glds16(xh + aOff0 + kt, &sAh[ldsOff0]);
        glds16(xh + aOff1 + kt, &sAh[ldsOff1]);
        glds16(xl + aOff0 + kt, &sAl[ldsOff0]);
        glds16(xl + aOff1 + kt, &sAl[ldsOff1]);
        glds16(wh + bOff0 + kt, &sBh[ldsOff0]);
        glds16(wh + bOff1 + kt, &sBh[ldsOff1]);
        glds16(wl + bOff0 + kt, &sBl[ldsOff0]);
        glds16(wl + bOff1 + kt, &sBl[ldsOff1]);
        __syncthreads();

#pragma unroll
        for (int ks = 0; ks < 32; ks += 16) {      // two 16-wide k substeps
            const int fo = ks + kq;
            bf16x8 ah[2], al[2], bh[2], bl[2];
#pragma unroll
            for (int t = 0; t < 2; ++t) {
                const int ra = (wr + t * 32 + rowin) * 32 + fo;
                const int rb = (wc + t * 32 + rowin) * 32 + fo;
                ah[t] = *(const bf16x8*)&sAh[ra];
                al[t] = *(const bf16x8*)&sAl[ra];
                bh[t] = *(const bf16x8*)&sBh[rb];
                bl[t] = *(const bf16x8*)&sBl[rb];
            }
#pragma unroll
            for (int tr = 0; tr < 2; ++tr)
#pragma unroll
                for (int tc = 0; tc < 2; ++tc) {
                    acc[tr][tc] = __builtin_amdgcn_mfma_f32_32x32x16_bf16(ah[tr], bh[tc], acc[tr][tc], 0, 0, 0);
                    acc[tr][tc] = __builtin_amdgcn_mfma_f32_32x32x16_bf16(ah[tr], bl[tc], acc[tr][tc], 0, 0, 0);
                    acc[tr][tc] = __builtin_amdgcn_mfma_f32_32x32x16_bf16(al[tr], bh[tc], acc[tr][tc], 0, 0, 0);
                }
        }
        __syncthreads();
    }

    // epilogue: 32x32 C/D layout col = l&31, row = (r&3) + 8*(r>>2) + 4*(l>>5)  (m74/m101)
    const int cbase = (l >> 5) * 4;
    const int ccol  = l & 31;
#pragma unroll
    for (int tr = 0; tr < 2; ++tr)
#pragma unroll
        for (int tc = 0; tc < 2; ++tc) {
            const int col = n0 + wc + tc * 32 + ccol;
#pragma unroll
            for (int r = 0; r < 16; ++r) {
                const int row = m0 + wr + tr * 32 + (r & 3) + 8 * (r >> 2) + cbase;
                atomicAdd(g + (size_t)row * N_DIM + col, acc[tr][tc][r]);
            }
        }
}

// ---------- depthwise temporal conv + energy, LDS-staged weights ----------
// block = one (b, t, 256-filter chunk); thread = one filter.
__global__ __launch_bounds__(256) void conv_energy_kernel(
    const float* __restrict__ g,
    const float* __restrict__ wts,
    const float* __restrict__ wtc,
    float* __restrict__ out) {

    __shared__ float wl_c[16][256];
    __shared__ float wl_s[16][256];

    const int tid = threadIdx.x;
    const int bid = blockIdx.x;          // 19200 = 8 * 240 * 10
    const int fc  = bid % 10;
    const int t   = (bid / 10) % T_LEN;
    const int b   = bid / (10 * T_LEN);
    const int f0  = fc * 256;

    // cooperative weight load: thread tid owns filter f0+tid's 16 taps
    {
        const float4* wrc = (const float4*)(wtc + (size_t)(f0 + tid) * 16);
        const float4* wrs = (const float4*)(wts + (size_t)(f0 + tid) * 16);
#pragma unroll
        for (int k4 = 0; k4 < 4; ++k4) {
            const float4 vc = wrc[k4];
            const float4 vs = wrs[k4];
            wl_c[k4 * 4 + 0][tid] = vc.x; wl_c[k4 * 4 + 1][tid] = vc.y;
            wl_c[k4 * 4 + 2][tid] = vc.z; wl_c[k4 * 4 + 3][tid] = vc.w;
            wl_s[k4 * 4 + 0][tid] = vs.x; wl_s[k4 * 4 + 1][tid] = vs.y;
            wl_s[k4 * 4 + 2][tid] = vs.z; wl_s[k4 * 4 + 3][tid] = vs.w;
        }
    }
    __syncthreads();

    const float* grow = g + (size_t)b * T_LEN * N_DIM + f0 + tid;
    float s = 0.f, c = 0.f;
#pragma unroll
    for (int j = 0; j < 16; ++j) {
        const int tt = t + j - PAD_L;
        if (tt >= 0 && tt < T_LEN) {     // block-uniform branch (t fixed per block)
            const float gs = grow[(size_t)tt * N_DIM];
            const float gc = grow[(size_t)tt * N_DIM + NFILT];
            const float a  = wl_c[j][tid];
            const float bb = wl_s[j][tid];
            s += gs * a + gc * bb;
            c += gc * a - gs * bb;
        }
    }
    const float r = sqrtf(s * s + c * c);
    out[(size_t)((b * T_LEN + t) * NFILT) + f0 + tid] = logf(r + 1e-5f);
}

extern "C" void kernel_launch(void* const* d_in, const int* in_sizes, int n_in,
                              void* d_out, int out_size, void* d_ws, size_t ws_size,
                              hipStream_t stream) {
    const float* x   = (const float*)d_in[0];  // (8,240,96,96)
    const float* wss = (const float*)d_in[1];  // (2560,96,96)
    const float* wsc = (const float*)d_in[2];  // (2560,96,96)
    const float* wts = (const float*)d_in[3];  // (2560,16)
    const float* wtc = (const float*)d_in[4];  // (2560,16)
    float* out = (float*)d_out;

    // workspace layout (bytes):
    //   xh: 35,389,440 | xl: 35,389,440 | wh: 94,371,840 | wl: 94,371,840 | g: 39,321,600
    char* ws = (char*)d_ws;
    u16*   xh  = (u16*)(ws);
    u16*   xl  = (u16*)(ws + 35389440);
    u16*   whi = (u16*)(ws + 70778880);
    u16*   wlo = (u16*)(ws + 165150720);
    float* g   = (float*)(ws + 259522560);

    hipMemsetAsync(g, 0, (size_t)M_DIM * N_DIM * 4, stream);

    const int ntot4 = NX4 + 2 * NW4;
    split_all_kernel<<<(ntot4 + 255) / 256, 256, 0, stream>>>(x, wss, wsc, xh, xl, whi, wlo);

    gemm_split_kernel<<<600 * KSPLIT, 256, 0, stream>>>(xh, xl, whi, wlo, g);

    conv_energy_kernel<<<B_SZ * T_LEN * 10, 256, 0, stream>>>(g, wts, wtc, out);
}